// Round 6
// baseline (1048.247 us; speedup 1.0000x reference)
//
#include <hip/hip_runtime.h>

#define HH 1024
#define WW 1024
#define NB 16
#define NTH 3
#define BAND 64
#define NBAND (HH/BAND)       // 16
#define NSTRIP 11             // strips of 128 cols, 96-col yield: 11*96 = 1056 >= 1024
#define ACC_BYTES 4096

// sigmoid(10*(v-th)) for th = 0, 0.5, 1.0 sharing one exp
__device__ __forceinline__ void sig3(float v, float* sf){
  const float e = __expf(-10.0f * v);
  sf[0] = __fdividef(1.0f, 1.0f + e);
  sf[1] = __fdividef(1.0f, 1.0f + e*148.41315910257660f);
  sf[2] = __fdividef(1.0f, 1.0f + e*22026.465794806718f);
}

__global__ __launch_bounds__(256, 4) void fss_fused(
    const float* __restrict__ F_, const float* __restrict__ O_,
    double* __restrict__ accum)
{
  const int tid = threadIdx.x;
  const int ln  = tid & 63;
  const int w   = (blockIdx.x << 2) + (tid >> 6);   // global wave id
  const int s   = w % NSTRIP;
  const int rem = w / NSTRIP;
  const int band = rem & (NBAND-1);
  const int img  = rem / NBAND;
  const int y0 = band * BAND;
  const int x0 = 96*s - 16 + 2*ln;                  // owned col pair (x0, x0+1)
  const bool colok = ((unsigned)x0 < WW);
  const bool act   = (ln >= 8) && (ln < 56) && colok;

  const float* F = F_ + (size_t)img*HH*WW;
  const float* O = O_ + (size_t)img*HH*WW;

  // vertical window state (f32 everywhere)
  float c9f[NTH][2]={{0}}, c9o[NTH][2]={{0}}, c33f[NTH][2]={{0}}, c33o[NTH][2]={{0}};
  float s1d[NTH]={0}, s1r[NTH]={0}, s9d[NTH]={0}, s9r[NTH]={0},
        s33d[NTH]={0}, s33r[NTH]={0};

  // hoisted shuffle source-lane indices
  const int i_p7=(ln+7)&63, i_m9=(ln-9)&63, i_p8=(ln+8)&63, i_m8=(ln-8)&63;
  const int i_m2=(ln-2)&63, i_m1=(ln-1)&63, i_p1=(ln+1)&63, i_q2=(ln+2)&63;

  // ---- warmup: rows [y0-16, y0+16] ----
  #pragma unroll 1
  for (int r = y0-16; r <= y0+16; ++r){
    if ((unsigned)r >= HH) continue;
    float2 fv = {0,0}, ov = {0,0};
    if (colok){
      fv = *(const float2*)&F[(size_t)r*WW + x0];
      ov = *(const float2*)&O[(size_t)r*WW + x0];
    }
    const bool in9  = (r >= y0-4) && (r <= y0+4);
    const bool ink1 = (r >= y0)   && (r <= y0+4);
    float sf0[3], sf1[3]; sig3(fv.x, sf0); sig3(fv.y, sf1);
    #pragma unroll
    for (int t = 0; t < NTH; ++t){
      const float th = 0.5f*(float)t;
      const float so0 = (ov.x > th) ? 1.f : 0.f, so1 = (ov.y > th) ? 1.f : 0.f;
      c33f[t][0] += sf0[t]; c33f[t][1] += sf1[t];
      c33o[t][0] += so0;    c33o[t][1] += so1;
      if (in9){ c9f[t][0] += sf0[t]; c9f[t][1] += sf1[t];
                c9o[t][0] += so0;    c9o[t][1] += so1; }
      if (ink1){
        const float d0 = sf0[t]-so0, d1 = sf1[t]-so1;
        s1d[t] += d0*d0 + d1*d1;
        s1r[t] += sf0[t]*sf0[t] + so0 + sf1[t]*sf1[t] + so1;   // so^2 == so
      }
    }
  }

  // ---- main loop: no barriers, no LDS ----
  #pragma unroll 1
  for (int y = y0; y < y0 + BAND; ++y){
    // issue boundary-row loads first (latency overlaps the shuffle phase)
    const int ri9 = y+5, ro9 = y-4, ri33 = y+17, ro33 = y-16;
    const bool bi9 = (ri9 < HH), bo9 = (ro9 >= 0), bi33 = (ri33 < HH), bo33 = (ro33 >= 0);
    float2 vi9f={0,0}, vi9o={0,0}, vo9f={0,0}, vo9o={0,0};
    float2 vi33f={0,0}, vi33o={0,0}, vo33f={0,0}, vo33o={0,0};
    if (colok){
      if (bi9 ){ vi9f  = *(const float2*)&F[(size_t)ri9 *WW + x0]; vi9o  = *(const float2*)&O[(size_t)ri9 *WW + x0]; }
      if (bo9 ){ vo9f  = *(const float2*)&F[(size_t)ro9 *WW + x0]; vo9o  = *(const float2*)&O[(size_t)ro9 *WW + x0]; }
      if (bi33){ vi33f = *(const float2*)&F[(size_t)ri33*WW + x0]; vi33o = *(const float2*)&O[(size_t)ri33*WW + x0]; }
      if (bo33){ vo33f = *(const float2*)&F[(size_t)ro33*WW + x0]; vo33o = *(const float2*)&O[(size_t)ro33*WW + x0]; }
    }

    // horizontal windows + stats for row y (state centered at y)
    #pragma unroll
    for (int t = 0; t < NTH; ++t){
      // 33-window via wave scan of column-pair sums
      float Sf = c33f[t][0] + c33f[t][1];
      float So = c33o[t][0] + c33o[t][1];
      #pragma unroll
      for (int d = 1; d < 64; d <<= 1){
        const float uf = __shfl_up(Sf, d, 64);
        const float uo = __shfl_up(So, d, 64);
        if (ln >= d){ Sf += uf; So += uo; }
      }
      const float Sfp7 = __shfl(Sf, i_p7, 64), Sop7 = __shfl(So, i_p7, 64);
      float Sfm9 = __shfl(Sf, i_m9, 64), Som9 = __shfl(So, i_m9, 64);
      if (ln < 9){ Sfm9 = 0.f; Som9 = 0.f; }
      const float Sfp8 = __shfl(Sf, i_p8, 64), Sop8 = __shfl(So, i_p8, 64);
      const float Sfm8 = __shfl(Sf, i_m8, 64), Som8 = __shfl(So, i_m8, 64);
      const float ef0 = __shfl(c33f[t][0], i_p8, 64);
      const float eo0 = __shfl(c33o[t][0], i_p8, 64);
      const float ef1 = __shfl(c33f[t][1], i_m8, 64);
      const float eo1 = __shfl(c33o[t][1], i_m8, 64);
      const float h33f0 = Sfp7 - Sfm9 + ef0;
      const float h33o0 = Sop7 - Som9 + eo0;
      const float h33f1 = Sfp8 - Sfm8 + ef1;
      const float h33o1 = Sop8 - Som8 + eo1;

      // 9-window via direct lane taps on column-pair sums
      const float qf = c9f[t][0] + c9f[t][1];
      const float qo = c9o[t][0] + c9o[t][1];
      const float qfm2 = __shfl(qf, i_m2, 64), qfm1 = __shfl(qf, i_m1, 64);
      const float qfp1 = __shfl(qf, i_p1, 64), qfp2 = __shfl(qf, i_q2, 64);
      const float qom2 = __shfl(qo, i_m2, 64), qom1 = __shfl(qo, i_m1, 64);
      const float qop1 = __shfl(qo, i_p1, 64), qop2 = __shfl(qo, i_q2, 64);
      const float gf0 = __shfl(c9f[t][0], i_q2, 64);
      const float go0 = __shfl(c9o[t][0], i_q2, 64);
      const float gf1 = __shfl(c9f[t][1], i_m2, 64);
      const float go1 = __shfl(c9o[t][1], i_m2, 64);
      const float h9f0 = qfm2 + qfm1 + qf + qfp1 + gf0;
      const float h9o0 = qom2 + qom1 + qo + qop1 + go0;
      const float h9f1 = gf1 + qfm1 + qf + qfp1 + qfp2;
      const float h9o1 = go1 + qom1 + qo + qop1 + qop2;

      const float F90 = h9f0*(1.f/81.f), O90 = h9o0*(1.f/81.f);
      const float F91 = h9f1*(1.f/81.f), O91 = h9o1*(1.f/81.f);
      const float d90 = F90-O90, d91 = F91-O91;
      s9d[t] += d90*d90 + d91*d91;
      s9r[t] += F90*F90 + O90*O90 + F91*F91 + O91*O91;
      const float Fa0 = h33f0*(1.f/1089.f), Oa0 = h33o0*(1.f/1089.f);
      const float Fa1 = h33f1*(1.f/1089.f), Oa1 = h33o1*(1.f/1089.f);
      const float da0 = Fa0-Oa0, da1 = Fa1-Oa1;
      s33d[t] += da0*da0 + da1*da1;
      s33r[t] += Fa0*Fa0 + Oa0*Oa0 + Fa1*Fa1 + Oa1*Oa1;
    }

    // slide vertical windows to center y+1 (+ k=1 stats on entering 9-row)
    if (bi9){
      float sf0[3], sf1[3]; sig3(vi9f.x, sf0); sig3(vi9f.y, sf1);
      const bool k1on = (ri9 < y0 + BAND);
      #pragma unroll
      for (int t = 0; t < NTH; ++t){
        const float th = 0.5f*(float)t;
        const float so0 = (vi9o.x > th) ? 1.f : 0.f, so1 = (vi9o.y > th) ? 1.f : 0.f;
        c9f[t][0] += sf0[t]; c9f[t][1] += sf1[t];
        c9o[t][0] += so0;    c9o[t][1] += so1;
        if (k1on){
          const float d0 = sf0[t]-so0, d1 = sf1[t]-so1;
          s1d[t] += d0*d0 + d1*d1;
          s1r[t] += sf0[t]*sf0[t] + so0 + sf1[t]*sf1[t] + so1;
        }
      }
    }
    if (bo9){
      float sf0[3], sf1[3]; sig3(vo9f.x, sf0); sig3(vo9f.y, sf1);
      #pragma unroll
      for (int t = 0; t < NTH; ++t){
        const float th = 0.5f*(float)t;
        const float so0 = (vo9o.x > th) ? 1.f : 0.f, so1 = (vo9o.y > th) ? 1.f : 0.f;
        c9f[t][0] -= sf0[t]; c9f[t][1] -= sf1[t];
        c9o[t][0] -= so0;    c9o[t][1] -= so1;
      }
    }
    if (bi33){
      float sf0[3], sf1[3]; sig3(vi33f.x, sf0); sig3(vi33f.y, sf1);
      #pragma unroll
      for (int t = 0; t < NTH; ++t){
        const float th = 0.5f*(float)t;
        const float so0 = (vi33o.x > th) ? 1.f : 0.f, so1 = (vi33o.y > th) ? 1.f : 0.f;
        c33f[t][0] += sf0[t]; c33f[t][1] += sf1[t];
        c33o[t][0] += so0;    c33o[t][1] += so1;
      }
    }
    if (bo33){
      float sf0[3], sf1[3]; sig3(vo33f.x, sf0); sig3(vo33f.y, sf1);
      #pragma unroll
      for (int t = 0; t < NTH; ++t){
        const float th = 0.5f*(float)t;
        const float so0 = (vo33o.x > th) ? 1.f : 0.f, so1 = (vo33o.y > th) ? 1.f : 0.f;
        c33f[t][0] -= sf0[t]; c33f[t][1] -= sf1[t];
        c33o[t][0] -= so0;    c33o[t][1] -= so1;
      }
    }
  }

  // ---- mask halo lanes, wave-reduce, per-wave f64 atomics ----
  if (!act){
    #pragma unroll
    for (int t = 0; t < NTH; ++t){
      s1d[t]=0; s1r[t]=0; s9d[t]=0; s9r[t]=0; s33d[t]=0; s33r[t]=0;
    }
  }
  #define WRED(v) { _Pragma("unroll") \
    for (int d = 32; d; d >>= 1) v += __shfl_down(v, (unsigned)d, 64); }
  #pragma unroll
  for (int t = 0; t < NTH; ++t){
    WRED(s1d[t]);  WRED(s1r[t]);
    WRED(s9d[t]);  WRED(s9r[t]);
    WRED(s33d[t]); WRED(s33r[t]);
  }
  if (ln == 0){
    #pragma unroll
    for (int t = 0; t < NTH; ++t){
      double* a = accum + (size_t)(img*NTH + t)*6;
      atomicAdd(&a[0], (double)s1d[t]);
      atomicAdd(&a[1], (double)s1r[t]);
      atomicAdd(&a[2], (double)s9d[t]);
      atomicAdd(&a[3], (double)s9r[t]);
      atomicAdd(&a[4], (double)s33d[t]);
      atomicAdd(&a[5], (double)s33r[t]);
    }
  }
}

__global__ void fss_final(const double* __restrict__ accum, float* __restrict__ out)
{
  if (threadIdx.x == 0 && blockIdx.x == 0){
    const double HW = (double)HH * (double)WW;
    double total = 0.0;
    for (int t = 0; t < NTH; ++t){
      for (int k = 0; k < 3; ++k){
        double s = 0.0;
        for (int img = 0; img < NB; ++img){
          const double* a = accum + (size_t)(img*NTH + t)*6 + (size_t)k*2;
          const double mse  = a[0] / HW;
          const double mref = a[1] / HW;
          s += 1.0 - mse / (mref + 1e-8);
        }
        total += s / (double)NB;
      }
    }
    out[0] = (float)(1.0 - total/9.0);
  }
}

extern "C" void kernel_launch(void* const* d_in, const int* in_sizes, int n_in,
                              void* d_out, int out_size, void* d_ws, size_t ws_size,
                              hipStream_t stream)
{
  const float* fcst = (const float*)d_in[0];
  const float* obs  = (const float*)d_in[1];
  float* out = (float*)d_out;
  double* accum = (double*)d_ws;

  const int nwaves = NSTRIP * NBAND * NB;   // 2816
  const int nblocks = nwaves / 4;           // 704

  hipMemsetAsync(d_ws, 0, ACC_BYTES, stream);
  hipLaunchKernelGGL(fss_fused, dim3(nblocks), dim3(256), 0, stream,
                     fcst, obs, accum);
  hipLaunchKernelGGL(fss_final, dim3(1), dim3(64), 0, stream, accum, out);
}

// Round 7
// 330.926 us; speedup vs baseline: 3.1676x; 3.1676x over previous
//
#include <hip/hip_runtime.h>

#define HH 1024
#define WW 1024
#define NB 16
#define NTH 3
#define BAND 64
#define NBAND (HH/BAND)       // 16
#define NSTRIP 11             // strips of 128 cols, 96-col yield: 11*96 = 1056 >= 1024
#define ACC_BYTES 4096

// sigmoid(10*(v-th)) for th = 0, 0.5, 1.0 sharing one exp
__device__ __forceinline__ void sig3(float v, float* sf){
  const float e = __expf(-10.0f * v);
  sf[0] = __fdividef(1.0f, 1.0f + e);
  sf[1] = __fdividef(1.0f, 1.0f + e*148.41315910257660f);
  sf[2] = __fdividef(1.0f, 1.0f + e*22026.465794806718f);
}

__device__ __forceinline__ float bp(int idx4, float v){
  return __int_as_float(__builtin_amdgcn_ds_bpermute(idx4, __float_as_int(v)));
}

__global__ __launch_bounds__(256) void fss_fused(
    const float* __restrict__ F_, const float* __restrict__ O_,
    double* __restrict__ accum)
{
  const int tid = threadIdx.x;
  const int ln  = tid & 63;
  const int w   = (blockIdx.x << 2) + (tid >> 6);   // global wave id
  const int s   = w % NSTRIP;
  const int rem = w / NSTRIP;
  const int band = rem & (NBAND-1);
  const int img  = rem / NBAND;
  const int y0 = band * BAND;
  const int x0 = 96*s - 16 + 2*ln;                  // owned col pair (x0, x0+1)
  const bool colok = ((unsigned)x0 < WW);
  const bool act   = (ln >= 8) && (ln < 56) && colok;

  const float* F = F_ + (size_t)img*HH*WW;
  const float* O = O_ + (size_t)img*HH*WW;

  // vertical window state (f32 everywhere)
  float c9f[NTH][2]={{0}}, c9o[NTH][2]={{0}}, c33f[NTH][2]={{0}}, c33o[NTH][2]={{0}};
  float s1d[NTH]={0}, s1r[NTH]={0}, s9d[NTH]={0}, s9r[NTH]={0},
        s33d[NTH]={0}, s33r[NTH]={0};

  // precomputed ds_bpermute byte indices (lane index << 2, wrap &63)
  const int i_m1 = ((ln-1)&63)<<2, i_m2 = ((ln-2)&63)<<2;
  const int i_m4 = ((ln-4)&63)<<2, i_m8 = ((ln-8)&63)<<2;
  const int i_p1 = ((ln+1)&63)<<2, i_p2 = ((ln+2)&63)<<2;
  const int i_p7 = ((ln+7)&63)<<2, i_p8 = ((ln+8)&63)<<2;

  // ---- warmup: rows [y0-16, y0+16] ----
  #pragma unroll 1
  for (int r = y0-16; r <= y0+16; ++r){
    if ((unsigned)r >= HH) continue;
    float2 fv = {0,0}, ov = {0,0};
    if (colok){
      fv = *(const float2*)&F[(size_t)r*WW + x0];
      ov = *(const float2*)&O[(size_t)r*WW + x0];
    }
    const bool in9  = (r >= y0-4) && (r <= y0+4);
    const bool ink1 = (r >= y0)   && (r <= y0+4);
    float sf0[3], sf1[3]; sig3(fv.x, sf0); sig3(fv.y, sf1);
    #pragma unroll
    for (int t = 0; t < NTH; ++t){
      const float th = 0.5f*(float)t;
      const float so0 = (ov.x > th) ? 1.f : 0.f, so1 = (ov.y > th) ? 1.f : 0.f;
      c33f[t][0] += sf0[t]; c33f[t][1] += sf1[t];
      c33o[t][0] += so0;    c33o[t][1] += so1;
      if (in9){ c9f[t][0] += sf0[t]; c9f[t][1] += sf1[t];
                c9o[t][0] += so0;    c9o[t][1] += so1; }
      if (ink1){
        const float d0 = sf0[t]-so0, d1 = sf1[t]-so1;
        s1d[t] += d0*d0 + d1*d1;
        s1r[t] += sf0[t]*sf0[t] + so0 + sf1[t]*sf1[t] + so1;   // so^2 == so
      }
    }
  }

  // ---- main loop: no barriers, no LDS (bpermute only) ----
  #pragma unroll 1
  for (int y = y0; y < y0 + BAND; ++y){
    // issue boundary-row loads first (latency overlaps the shuffle phase)
    const int ri9 = y+5, ro9 = y-4, ri33 = y+17, ro33 = y-16;
    const bool bi9 = (ri9 < HH), bo9 = (ro9 >= 0), bi33 = (ri33 < HH), bo33 = (ro33 >= 0);
    float2 vi9f={0,0}, vi9o={0,0}, vo9f={0,0}, vo9o={0,0};
    float2 vi33f={0,0}, vi33o={0,0}, vo33f={0,0}, vo33o={0,0};
    if (colok){
      if (bi9 ){ vi9f  = *(const float2*)&F[(size_t)ri9 *WW + x0]; vi9o  = *(const float2*)&O[(size_t)ri9 *WW + x0]; }
      if (bo9 ){ vo9f  = *(const float2*)&F[(size_t)ro9 *WW + x0]; vo9o  = *(const float2*)&O[(size_t)ro9 *WW + x0]; }
      if (bi33){ vi33f = *(const float2*)&F[(size_t)ri33*WW + x0]; vi33o = *(const float2*)&O[(size_t)ri33*WW + x0]; }
      if (bo33){ vo33f = *(const float2*)&F[(size_t)ro33*WW + x0]; vo33o = *(const float2*)&O[(size_t)ro33*WW + x0]; }
    }

    // horizontal windows + stats for row y (state centered at y)
    #pragma unroll
    for (int t = 0; t < NTH; ++t){
      // ---- 33-window via unmasked window tree over column-pair sums ----
      // w16[l] = sum S[l-15..l]; wrap garbage confined to halo lanes (<8):
      // taps only use w16[l+7], w16[l+8] which need l>=8.
      const float Sf = c33f[t][0] + c33f[t][1];
      const float So = c33o[t][0] + c33o[t][1];
      float wf = Sf + bp(i_m1, Sf);
      float wo = So + bp(i_m1, So);
      wf += bp(i_m2, wf);  wo += bp(i_m2, wo);
      wf += bp(i_m4, wf);  wo += bp(i_m4, wo);
      wf += bp(i_m8, wf);  wo += bp(i_m8, wo);
      const float h33f0 = bp(i_p7, wf) + bp(i_p8, c33f[t][0]);
      const float h33o0 = bp(i_p7, wo) + bp(i_p8, c33o[t][0]);
      const float h33f1 = bp(i_p8, wf) + bp(i_m8, c33f[t][1]);
      const float h33o1 = bp(i_p8, wo) + bp(i_m8, c33o[t][1]);

      // ---- 9-window via direct lane taps on column-pair sums ----
      const float qf = c9f[t][0] + c9f[t][1];
      const float qo = c9o[t][0] + c9o[t][1];
      const float qfm1 = bp(i_m1, qf), qfp1 = bp(i_p1, qf);
      const float qom1 = bp(i_m1, qo), qop1 = bp(i_p1, qo);
      const float h9f0 = bp(i_m2, qf) + qfm1 + qf + qfp1 + bp(i_p2, c9f[t][0]);
      const float h9o0 = bp(i_m2, qo) + qom1 + qo + qop1 + bp(i_p2, c9o[t][0]);
      const float h9f1 = bp(i_m2, c9f[t][1]) + qfm1 + qf + qfp1 + bp(i_p2, qf);
      const float h9o1 = bp(i_m2, c9o[t][1]) + qom1 + qo + qop1 + bp(i_p2, qo);

      const float F90 = h9f0*(1.f/81.f), O90 = h9o0*(1.f/81.f);
      const float F91 = h9f1*(1.f/81.f), O91 = h9o1*(1.f/81.f);
      const float d90 = F90-O90, d91 = F91-O91;
      s9d[t] += d90*d90 + d91*d91;
      s9r[t] += F90*F90 + O90*O90 + F91*F91 + O91*O91;
      const float Fa0 = h33f0*(1.f/1089.f), Oa0 = h33o0*(1.f/1089.f);
      const float Fa1 = h33f1*(1.f/1089.f), Oa1 = h33o1*(1.f/1089.f);
      const float da0 = Fa0-Oa0, da1 = Fa1-Oa1;
      s33d[t] += da0*da0 + da1*da1;
      s33r[t] += Fa0*Fa0 + Oa0*Oa0 + Fa1*Fa1 + Oa1*Oa1;
    }

    // slide vertical windows to center y+1 (+ k=1 stats on entering 9-row)
    if (bi9){
      float sf0[3], sf1[3]; sig3(vi9f.x, sf0); sig3(vi9f.y, sf1);
      const bool k1on = (ri9 < y0 + BAND);
      #pragma unroll
      for (int t = 0; t < NTH; ++t){
        const float th = 0.5f*(float)t;
        const float so0 = (vi9o.x > th) ? 1.f : 0.f, so1 = (vi9o.y > th) ? 1.f : 0.f;
        c9f[t][0] += sf0[t]; c9f[t][1] += sf1[t];
        c9o[t][0] += so0;    c9o[t][1] += so1;
        if (k1on){
          const float d0 = sf0[t]-so0, d1 = sf1[t]-so1;
          s1d[t] += d0*d0 + d1*d1;
          s1r[t] += sf0[t]*sf0[t] + so0 + sf1[t]*sf1[t] + so1;
        }
      }
    }
    if (bo9){
      float sf0[3], sf1[3]; sig3(vo9f.x, sf0); sig3(vo9f.y, sf1);
      #pragma unroll
      for (int t = 0; t < NTH; ++t){
        const float th = 0.5f*(float)t;
        const float so0 = (vo9o.x > th) ? 1.f : 0.f, so1 = (vo9o.y > th) ? 1.f : 0.f;
        c9f[t][0] -= sf0[t]; c9f[t][1] -= sf1[t];
        c9o[t][0] -= so0;    c9o[t][1] -= so1;
      }
    }
    if (bi33){
      float sf0[3], sf1[3]; sig3(vi33f.x, sf0); sig3(vi33f.y, sf1);
      #pragma unroll
      for (int t = 0; t < NTH; ++t){
        const float th = 0.5f*(float)t;
        const float so0 = (vi33o.x > th) ? 1.f : 0.f, so1 = (vi33o.y > th) ? 1.f : 0.f;
        c33f[t][0] += sf0[t]; c33f[t][1] += sf1[t];
        c33o[t][0] += so0;    c33o[t][1] += so1;
      }
    }
    if (bo33){
      float sf0[3], sf1[3]; sig3(vo33f.x, sf0); sig3(vo33f.y, sf1);
      #pragma unroll
      for (int t = 0; t < NTH; ++t){
        const float th = 0.5f*(float)t;
        const float so0 = (vo33o.x > th) ? 1.f : 0.f, so1 = (vo33o.y > th) ? 1.f : 0.f;
        c33f[t][0] -= sf0[t]; c33f[t][1] -= sf1[t];
        c33o[t][0] -= so0;    c33o[t][1] -= so1;
      }
    }
  }

  // ---- mask halo lanes, wave-reduce, per-wave f64 atomics ----
  if (!act){
    #pragma unroll
    for (int t = 0; t < NTH; ++t){
      s1d[t]=0; s1r[t]=0; s9d[t]=0; s9r[t]=0; s33d[t]=0; s33r[t]=0;
    }
  }
  #define WRED(v) { _Pragma("unroll") \
    for (int d = 32; d; d >>= 1) v += __shfl_down(v, (unsigned)d, 64); }
  #pragma unroll
  for (int t = 0; t < NTH; ++t){
    WRED(s1d[t]);  WRED(s1r[t]);
    WRED(s9d[t]);  WRED(s9r[t]);
    WRED(s33d[t]); WRED(s33r[t]);
  }
  if (ln == 0){
    #pragma unroll
    for (int t = 0; t < NTH; ++t){
      double* a = accum + (size_t)(img*NTH + t)*6;
      atomicAdd(&a[0], (double)s1d[t]);
      atomicAdd(&a[1], (double)s1r[t]);
      atomicAdd(&a[2], (double)s9d[t]);
      atomicAdd(&a[3], (double)s9r[t]);
      atomicAdd(&a[4], (double)s33d[t]);
      atomicAdd(&a[5], (double)s33r[t]);
    }
  }
}

__global__ void fss_final(const double* __restrict__ accum, float* __restrict__ out)
{
  if (threadIdx.x == 0 && blockIdx.x == 0){
    const double HW = (double)HH * (double)WW;
    double total = 0.0;
    for (int t = 0; t < NTH; ++t){
      for (int k = 0; k < 3; ++k){
        double s = 0.0;
        for (int img = 0; img < NB; ++img){
          const double* a = accum + (size_t)(img*NTH + t)*6 + (size_t)k*2;
          const double mse  = a[0] / HW;
          const double mref = a[1] / HW;
          s += 1.0 - mse / (mref + 1e-8);
        }
        total += s / (double)NB;
      }
    }
    out[0] = (float)(1.0 - total/9.0);
  }
}

extern "C" void kernel_launch(void* const* d_in, const int* in_sizes, int n_in,
                              void* d_out, int out_size, void* d_ws, size_t ws_size,
                              hipStream_t stream)
{
  const float* fcst = (const float*)d_in[0];
  const float* obs  = (const float*)d_in[1];
  float* out = (float*)d_out;
  double* accum = (double*)d_ws;

  const int nwaves = NSTRIP * NBAND * NB;   // 2816
  const int nblocks = nwaves / 4;           // 704

  hipMemsetAsync(d_ws, 0, ACC_BYTES, stream);
  hipLaunchKernelGGL(fss_fused, dim3(nblocks), dim3(256), 0, stream,
                     fcst, obs, accum);
  hipLaunchKernelGGL(fss_final, dim3(1), dim3(64), 0, stream, accum, out);
}